// Round 16
// baseline (167.287 us; speedup 1.0000x reference)
//
#include <hip/hip_runtime.h>

// ROI bilinear pooling (TF1 resize_images align_corners=False semantics).
// img: (1, 100, 100, 1024) f32 NHWC ; rois: (1, 512, 4) f32 (int-valued x,y,w,h)
// out: (1, 512, 7, 7, 1024) f32
//
// v6: store-batching probe. Each block owns a contiguous run of ~12-13
// positions (v2b XCD-chunked mapping); computes 4 positions into registers,
// then emits 4 back-to-back nontemporal stores = one 16 KB contiguous write
// burst per block (vs 4 KB interleaved with reads previously). Tests the
// read/write-mixing-penalty theory for the invariant ~62 us floor
// (TCC-level ~230 MB at 3.5-4.1 TB/s vs 6.3 TB/s write-only fills).
// Reads/geometry/occupancy levers unchanged (all previously measured null).

#define IMG_H 100
#define IMG_W 100
#define IMG_C 1024
#define N_ROI 512
#define POOLP 7
#define NPOS  (N_ROI * POOLP * POOLP)   // 25088
#define NBLK  2048                       // 8 blocks/CU

typedef float f32x4 __attribute__((ext_vector_type(4)));

__device__ __forceinline__ f32x4 compute_pos(
    const float* __restrict__ img, const float* __restrict__ rois,
    int p, int c)
{
    const int roi = p / 49;
    const int pos = p - roi * 49;
    const int py  = pos / 7;
    const int px  = pos - py * 7;

    const f32x4 rv = *reinterpret_cast<const f32x4*>(rois + roi * 4);
    const int x = (int)rv.x;
    const int y = (int)rv.y;
    const int w = (int)rv.z;
    const int h = (int)rv.w;

    // keep EXACT reference math: s = out_idx * (size / 7.0f), floor
    const float sx  = (float)px * ((float)w / (float)POOLP);
    const int   ix0 = (int)floorf(sx);
    const int   ix1 = min(ix0 + 1, w - 1);
    const float fx  = sx - (float)ix0;
    const int ax0 = min(max(x + ix0, 0), IMG_W - 1);
    const int ax1 = min(max(x + ix1, 0), IMG_W - 1);

    const float sy  = (float)py * ((float)h / (float)POOLP);
    const int   iy0 = (int)floorf(sy);
    const int   iy1 = min(iy0 + 1, h - 1);
    const float fy  = sy - (float)iy0;
    const int ay0 = min(max(y + iy0, 0), IMG_H - 1);
    const int ay1 = min(max(y + iy1, 0), IMG_H - 1);

    const f32x4 v00 = *reinterpret_cast<const f32x4*>(img + (size_t)(ay0 * IMG_W + ax0) * IMG_C + c);
    const f32x4 v01 = *reinterpret_cast<const f32x4*>(img + (size_t)(ay0 * IMG_W + ax1) * IMG_C + c);
    const f32x4 v10 = *reinterpret_cast<const f32x4*>(img + (size_t)(ay1 * IMG_W + ax0) * IMG_C + c);
    const f32x4 v11 = *reinterpret_cast<const f32x4*>(img + (size_t)(ay1 * IMG_W + ax1) * IMG_C + c);

    const float gx = 1.0f - fx;
    const float gy = 1.0f - fy;
    f32x4 top = v00 * gx + v01 * fx;
    f32x4 bot = v10 * gx + v11 * fx;
    return top * gy + bot * fy;
}

__global__ __launch_bounds__(256, 4) void roi_pool_kernel(
    const float* __restrict__ img,
    const float* __restrict__ rois,
    float* __restrict__ out)
{
    const int b = blockIdx.x;
    // XCD-chunked swizzle: contiguous position range per chunk-id.
    const int cid = ((b & 7) << 8) | (b >> 3);        // NBLK/8 == 256
    const int p0  = (int)(((long long)cid       * NPOS) / NBLK);
    const int p1  = (int)(((long long)(cid + 1) * NPOS) / NBLK);

    const int c = threadIdx.x << 2;   // 4 channels per thread

    int p = p0;
    // batches of 4 positions: compute into registers, then one 16 KB
    // contiguous store burst (4 positions x 4 KB, block-wide).
    for (; p + 4 <= p1; p += 4) {
        const f32x4 o0 = compute_pos(img, rois, p + 0, c);
        const f32x4 o1 = compute_pos(img, rois, p + 1, c);
        const f32x4 o2 = compute_pos(img, rois, p + 2, c);
        const f32x4 o3 = compute_pos(img, rois, p + 3, c);
        float* ob = out + (size_t)p * IMG_C + c;
        __builtin_nontemporal_store(o0, reinterpret_cast<f32x4*>(ob));
        __builtin_nontemporal_store(o1, reinterpret_cast<f32x4*>(ob + IMG_C));
        __builtin_nontemporal_store(o2, reinterpret_cast<f32x4*>(ob + 2 * IMG_C));
        __builtin_nontemporal_store(o3, reinterpret_cast<f32x4*>(ob + 3 * IMG_C));
    }
    // tail
    for (; p < p1; ++p) {
        const f32x4 o = compute_pos(img, rois, p, c);
        __builtin_nontemporal_store(
            o, reinterpret_cast<f32x4*>(out + (size_t)p * IMG_C + c));
    }
}

extern "C" void kernel_launch(void* const* d_in, const int* in_sizes, int n_in,
                              void* d_out, int out_size, void* d_ws, size_t ws_size,
                              hipStream_t stream)
{
    const float* img  = (const float*)d_in[0];
    const float* rois = (const float*)d_in[1];
    float* out = (float*)d_out;

    roi_pool_kernel<<<NBLK, 256, 0, stream>>>(img, rois, out);
}